// Round 9
// baseline (236.923 us; speedup 1.0000x reference)
//
#include <hip/hip_runtime.h>
#include <hip/hip_bf16.h>
#include <stdint.h>

typedef __attribute__((ext_vector_type(8)))  __bf16 bf16x8;
typedef __attribute__((ext_vector_type(4)))  float  f32x4;
typedef __attribute__((ext_vector_type(16))) float  f32x16;
typedef __hip_bfloat16 bf16_t;

#define T_SEQ 2048
#define D_MODEL 1024
#define N_HEADS 16
#define N_KV 4
#define HD 64
#define LDQKV 1536
#define KDIM 1024

// Convert 16 consecutive fp32 (4x float4) -> 16 bf16 (2x int4)
__device__ inline void cvt16(const float4* __restrict__ g, int4* __restrict__ s) {
  float4 v0 = g[0], v1 = g[1], v2 = g[2], v3 = g[3];
  union { int4 i[2]; __hip_bfloat162 h[8]; } u;
  u.h[0] = __float22bfloat162_rn(make_float2(v0.x, v0.y));
  u.h[1] = __float22bfloat162_rn(make_float2(v0.z, v0.w));
  u.h[2] = __float22bfloat162_rn(make_float2(v1.x, v1.y));
  u.h[3] = __float22bfloat162_rn(make_float2(v1.z, v1.w));
  u.h[4] = __float22bfloat162_rn(make_float2(v2.x, v2.y));
  u.h[5] = __float22bfloat162_rn(make_float2(v2.z, v2.w));
  u.h[6] = __float22bfloat162_rn(make_float2(v3.x, v3.y));
  u.h[7] = __float22bfloat162_rn(make_float2(v3.z, v3.w));
  s[0] = u.i[0]; s[1] = u.i[1];
}

__device__ inline void storeC(bf16_t* p, float v) { *p = __float2bfloat16(v); }
__device__ inline void storeC(float* p, float v) { *p = v; }

// v_permlane32_swap_b32 vdst, vsrc: after plswap(a,b): a={a_L,b_L}, b={a_U,b_U}
__device__ inline void plswap(unsigned& a, unsigned& b) {
  asm volatile("v_permlane32_swap_b32 %0, %1" : "+v"(a), "+v"(b));
}

// ---------------------------------------------------------------------------
// GEMM (unchanged — passing)
// ---------------------------------------------------------------------------
template <bool A_F32, typename CT>
__global__ __launch_bounds__(256) void gemm_bt(
    const void* __restrict__ Ap,
    const float* __restrict__ W0, const float* __restrict__ W1,
    const float* __restrict__ W2,
    CT* __restrict__ C, const int ldC)
{
  __shared__ bf16_t As[128 * 32];
  __shared__ bf16_t Bs[128 * 32];
  const int tid = threadIdx.x;
  const int lane = tid & 63;
  const int wv = tid >> 6;
  const int wr = wv >> 1, wc = wv & 1;
  const int m0 = blockIdx.y * 128;
  const int n0 = blockIdx.x * 128;
  const float* W = W0; int nr0 = n0;
  if (n0 >= 1280)      { W = W2; nr0 = n0 - 1280; }
  else if (n0 >= 1024) { W = W1; nr0 = n0 - 1024; }

  const int ra = tid >> 1;
  const int ca = (tid & 1) * 16;
  const float*  paf = (const float*)Ap  + (size_t)(m0 + ra) * KDIM + ca;
  const bf16_t* pah = (const bf16_t*)Ap + (size_t)(m0 + ra) * KDIM + ca;
  const float*  pb  = W + (size_t)(nr0 + ra) * KDIM + ca;
  int4* sa = (int4*)(&As[ra * 32 + ca]);
  int4* sb = (int4*)(&Bs[ra * 32 + ca]);

  f32x4 acc[4][4];
#pragma unroll
  for (int m = 0; m < 4; ++m)
#pragma unroll
    for (int n = 0; n < 4; ++n)
      acc[m][n] = {0.f, 0.f, 0.f, 0.f};

  const int fr = lane & 15;
  const int fq = lane >> 4;

  for (int k0 = 0; k0 < KDIM; k0 += 32) {
    if constexpr (A_F32) {
      cvt16((const float4*)(paf + k0), sa);
    } else {
      const int4* ga = (const int4*)(pah + k0);
      int4 a0 = ga[0], a1 = ga[1];
      sa[0] = a0; sa[1] = a1;
    }
    cvt16((const float4*)(pb + k0), sb);
    __syncthreads();
    bf16x8 af[4], bfv[4];
#pragma unroll
    for (int m = 0; m < 4; ++m)
      af[m] = *(const bf16x8*)(&As[(wr * 64 + m * 16 + fr) * 32 + fq * 8]);
#pragma unroll
    for (int n = 0; n < 4; ++n)
      bfv[n] = *(const bf16x8*)(&Bs[(wc * 64 + n * 16 + fr) * 32 + fq * 8]);
#pragma unroll
    for (int m = 0; m < 4; ++m)
#pragma unroll
      for (int n = 0; n < 4; ++n)
        acc[m][n] = __builtin_amdgcn_mfma_f32_16x16x32_bf16(af[m], bfv[n],
                                                            acc[m][n], 0, 0, 0);
    __syncthreads();
  }

#pragma unroll
  for (int m = 0; m < 4; ++m)
#pragma unroll
    for (int n = 0; n < 4; ++n)
#pragma unroll
      for (int r = 0; r < 4; ++r) {
        const int row = wr * 64 + m * 16 + fq * 4 + r;
        const int col = wc * 64 + n * 16 + fr;
        storeC(&C[(size_t)(m0 + row) * ldC + n0 + col], acc[m][n][r]);
      }
}

// ---------------------------------------------------------------------------
// RMSNorm + RoPE (unchanged — passing)
// ---------------------------------------------------------------------------
__global__ __launch_bounds__(256) void rms_rope(
    bf16_t* __restrict__ qkv, const float* __restrict__ cosb,
    const float* __restrict__ sinb, const float* __restrict__ qs,
    const float* __restrict__ ks)
{
  const int row = blockIdx.x;
  const int t = row & (T_SEQ - 1);
  const int tid = threadIdx.x;
  const int lane = tid & 63;
  const int wv = tid >> 6;
  const int f = lane & 15;
  const float c = (lane < 32) ? cosb[t * 16 + f] : 0.f;
  const float s = (lane < 32) ? sinb[t * 16 + f] : 0.f;
  for (int hh = wv; hh < 20; hh += 4) {
    const size_t idx = (size_t)row * LDQKV + hh * 64 + lane;
    const float v = __bfloat162float(qkv[idx]);
    float ssum = v * v;
#pragma unroll
    for (int off = 32; off; off >>= 1) ssum += __shfl_xor(ssum, off);
    const float norm = rsqrtf(ssum * (1.f / 64.f) + 1e-6f);
    const float scale = (hh < 16 ? qs : ks)[lane];
    float val = v * norm * scale;
    const float partner = __shfl_xor(val, 16);
    if (lane < 16)      val = val * c - partner * s;
    else if (lane < 32) val = partner * s + val * c;
    qkv[idx] = __float2bfloat16(val);
  }
}

// ---------------------------------------------------------------------------
// V transpose (unchanged — passing)
// ---------------------------------------------------------------------------
__global__ __launch_bounds__(256) void v_transpose(
    const bf16_t* __restrict__ qkv, bf16_t* __restrict__ v_t)
{
  __shared__ bf16_t tile[64 * 72];
  const int g = blockIdx.x;
  const int t0 = blockIdx.y * 64;
  const int tid = threadIdx.x;
  const int i = tid >> 2;
  const int dc = (tid & 3) * 16;
  const bf16_t* src = qkv + (size_t)((g >> 2) * T_SEQ + t0 + i) * LDQKV
                      + 1280 + (g & 3) * HD + dc;
  const int4* gs = (const int4*)src;
  int4 x0 = gs[0], x1 = gs[1];
  int4* st = (int4*)(&tile[i * 72 + dc]);
  st[0] = x0; st[1] = x1;
  __syncthreads();
  union { int4 v[2]; bf16_t h[16]; } u;
#pragma unroll
  for (int j = 0; j < 16; ++j) u.h[j] = tile[(dc + j) * 72 + i];
  int4* dst = (int4*)(v_t + (size_t)(g * HD + i) * T_SEQ + t0 + dc);
  dst[0] = u.v[0]; dst[1] = u.v[1];
}

// ---------------------------------------------------------------------------
// Causal GQA flash attention v6 — de-paired strips for 2x wave parallelism:
// block = 4 waves = strips 4sb..4sb+3 (one strip per wave), grid 1024 blocks
// = 4096 waves = 16 waves/CU. Cooperative LDS staging (coalesced, dbuf).
// V swizzle fixed: slot ^= (d>>1)&3 -> 8 distinct bank-groups per 8 d-rows.
// LDS map (int4 units): K buf: [b*512 + k*8 + (slot ^ (k&7))]
//                       V buf: [256 + b*512 + d*4 + (slot ^ ((d>>1)&3))]
// ---------------------------------------------------------------------------
__global__ __launch_bounds__(256) void attn(
    const bf16_t* __restrict__ qkv, const bf16_t* __restrict__ v_t,
    bf16_t* __restrict__ y)
{
  __shared__ int4 lds[1024];      // 16 KB: dbuf x (K 4KB + V 4KB)
  const int tid  = threadIdx.x;
  const int lane = tid & 63;
  const int wv   = tid >> 6;
  const int ql   = lane & 31;      // q within strip; also d_local for V frags
  const int hi   = lane >> 5;      // half-wave index
  // decode: same-(b,kvh) blocks share id%8 (XCD clustering); sb reversed so
  // longest blocks dispatch first.
  const int id   = (int)blockIdx.x;          // 0..1023
  const int low3 = id & 7;
  const int rest = id >> 3;                  // 0..127
  const int gsel = rest & 1;
  const int hh   = (rest >> 1) & 3;
  const int sbi  = rest >> 3;                // 0..15
  const int sb   = 15 - sbi;
  const int g16  = low3 + 8 * gsel;          // b*4+kvh
  const int b    = g16 >> 2, kvh = g16 & 3;
  const int h    = kvh * 4 + hh;
  const int s    = sb * 4 + wv;              // this wave's strip 0..63
  const int q_glob = s * 32 + ql;
  const int nt     = s + 1;                  // wave's tiles (last = diagonal)
  const int ntmax  = sb * 4 + 4;             // block-uniform staging count
  const float SCALE_LOG2 = 0.125f * 1.44269504089f;  // 1/sqrt(64)*log2(e)

  // --- per-thread staging addresses (tile-relative) ---
  const int kr = tid >> 3, kslot = tid & 7;          // K: row 0..31, 16B slot
  const int vd = tid >> 2, vslot = tid & 3;          // V: d-row 0..63, slot
  const bf16_t* gK = qkv + (size_t)(b * T_SEQ + kr) * LDQKV + 1024 + kvh * HD + kslot * 8;
  const bf16_t* gV = v_t + (size_t)((b * N_KV + kvh) * HD + vd) * T_SEQ + vslot * 8;
  const int wKidx = kr * 8 + (kslot ^ (kr & 7));
  const int wVidx = 256 + vd * 4 + (vslot ^ ((vd >> 1) & 3));

  // --- per-lane fragment read indices (tile-relative, int4 units) ---
  int kridx[4];
#pragma unroll
  for (int c = 0; c < 4; ++c)
    kridx[c] = ql * 8 + ((2 * c + hi) ^ (ql & 7));
  const int vsw = (ql >> 1) & 3;
  const int v0idx = 256 + ql * 4 + (hi ^ vsw);
  const int v1idx = 256 + ql * 4 + ((2 + hi) ^ vsw);
  const int v2idx = 256 + (ql + 32) * 4 + (hi ^ vsw);
  const int v3idx = 256 + (ql + 32) * 4 + ((2 + hi) ^ vsw);

  // Q fragments (B-operand), pre-scaled into log2 domain
  const bf16_t* Qrow = qkv + (size_t)(b * T_SEQ + q_glob) * LDQKV + h * HD + hi * 8;
  bf16x8 qfrag[4];
#pragma unroll
  for (int c = 0; c < 4; ++c) {
    bf16x8 raw = *(const bf16x8*)(Qrow + c * 16);
    bf16x8 sc;
#pragma unroll
    for (int j = 0; j < 8; ++j)
      sc[j] = (__bf16)((float)raw[j] * SCALE_LOG2);
    qfrag[c] = sc;
  }

  f32x16 acc0, acc1;
#pragma unroll
  for (int i = 0; i < 16; ++i) { acc0[i] = 0.f; acc1[i] = 0.f; }
  float m_run = -1e30f, l_run = 0.f;

  // prologue: stage tile 0 into buf 0
  {
    int4 kreg = *(const int4*)gK;
    int4 vreg = *(const int4*)gV;
    lds[wKidx] = kreg;
    lds[wVidx] = vreg;
  }
  __syncthreads();

  int buf = 0;
  for (int t = 0; t < ntmax; ++t) {
    // issue next tile's staging loads early (latency hides under compute)
    int4 kreg, vreg;
    const bool more = (t + 1 < ntmax);
    if (more) {
      kreg = *(const int4*)(gK + (size_t)(t + 1) * 32 * LDQKV);
      vreg = *(const int4*)(gV + (t + 1) * 32);
    }

    if (t < nt) {
      const int k0 = t << 5;
      const bool masked = (t == nt - 1);
      const int base = buf * 512;

      bf16x8 kf0 = *(const bf16x8*)&lds[base + kridx[0]];
      bf16x8 kf1 = *(const bf16x8*)&lds[base + kridx[1]];
      bf16x8 kf2 = *(const bf16x8*)&lds[base + kridx[2]];
      bf16x8 kf3 = *(const bf16x8*)&lds[base + kridx[3]];

      f32x16 st;
#pragma unroll
      for (int i = 0; i < 16; ++i) st[i] = 0.f;
      st = __builtin_amdgcn_mfma_f32_32x32x16_bf16(kf0, qfrag[0], st, 0, 0, 0);
      st = __builtin_amdgcn_mfma_f32_32x32x16_bf16(kf1, qfrag[1], st, 0, 0, 0);
      st = __builtin_amdgcn_mfma_f32_32x32x16_bf16(kf2, qfrag[2], st, 0, 0, 0);
      st = __builtin_amdgcn_mfma_f32_32x32x16_bf16(kf3, qfrag[3], st, 0, 0, 0);

      // softmax, in-register, log2 domain
      float sreg[16];
#pragma unroll
      for (int rr = 0; rr < 16; ++rr) sreg[rr] = st[rr];
      if (masked) {
#pragma unroll
        for (int rr = 0; rr < 16; ++rr) {
          const int kg = k0 + (rr & 3) + 8 * (rr >> 2) + 4 * hi;
          if (kg > q_glob) sreg[rr] = -1e30f;
        }
      }
      float bmax = fmaxf(fmaxf(fmaxf(sreg[0], sreg[1]), fmaxf(sreg[2], sreg[3])),
                         fmaxf(fmaxf(sreg[4], sreg[5]), fmaxf(sreg[6], sreg[7])));
      bmax = fmaxf(bmax,
             fmaxf(fmaxf(fmaxf(sreg[8], sreg[9]), fmaxf(sreg[10], sreg[11])),
                   fmaxf(fmaxf(sreg[12], sreg[13]), fmaxf(sreg[14], sreg[15]))));
      if (__any(bmax > m_run + 8.f)) {        // T13 defer-max
        const float rmax = fmaxf(bmax, __shfl_xor(bmax, 32));
        const float mnew = fmaxf(m_run, rmax);
        const float corr = exp2f(m_run - mnew);
#pragma unroll
        for (int i = 0; i < 16; ++i) { acc0[i] *= corr; acc1[i] *= corr; }
        l_run *= corr;
        m_run = mnew;
      }
      float pp[16];
      float lsum = 0.f;
#pragma unroll
      for (int rr = 0; rr < 16; ++rr) { pp[rr] = exp2f(sreg[rr] - m_run); lsum += pp[rr]; }
      lsum += __shfl_xor(lsum, 32);
      l_run += lsum;

      // pack P^T B-fragments via permlane32_swap
      union pk { __hip_bfloat162 h2; unsigned u; };
      unsigned w[8];
#pragma unroll
      for (int i = 0; i < 8; ++i) {
        pk t2; t2.h2 = __float22bfloat162_rn(make_float2(pp[2 * i], pp[2 * i + 1]));
        w[i] = t2.u;
      }
      plswap(w[0], w[2]); plswap(w[1], w[3]);
      plswap(w[4], w[6]); plswap(w[5], w[7]);
      union fu { unsigned u[4]; bf16x8 v; };
      fu f1, f2;
      f1.u[0] = w[0]; f1.u[1] = w[1]; f1.u[2] = w[2]; f1.u[3] = w[3];
      f2.u[0] = w[4]; f2.u[1] = w[5]; f2.u[2] = w[6]; f2.u[3] = w[7];

      bf16x8 vf0 = *(const bf16x8*)&lds[base + v0idx];
      bf16x8 vf1 = *(const bf16x8*)&lds[base + v1idx];
      bf16x8 vf2 = *(const bf16x8*)&lds[base + v2idx];
      bf16x8 vf3 = *(const bf16x8*)&lds[base + v3idx];

      acc0 = __builtin_amdgcn_mfma_f32_32x32x16_bf16(vf0, f1.v, acc0, 0, 0, 0);
      acc0 = __builtin_amdgcn_mfma_f32_32x32x16_bf16(vf1, f2.v, acc0, 0, 0, 0);
      acc1 = __builtin_amdgcn_mfma_f32_32x32x16_bf16(vf2, f1.v, acc1, 0, 0, 0);
      acc1 = __builtin_amdgcn_mfma_f32_32x32x16_bf16(vf3, f2.v, acc1, 0, 0, 0);
    }

    // write next tile into the other buffer (prev readers fenced by the
    // barrier at the end of the previous iteration)
    if (more) {
      const int nb = (buf ^ 1) * 512;
      lds[nb + wKidx] = kreg;
      lds[nb + wVidx] = vreg;
    }
    __syncthreads();
    buf ^= 1;
  }

  // epilogue: O = acc / l_run
  const float inv = 1.f / l_run;
  bf16_t* yrow = y + (size_t)(b * T_SEQ + q_glob) * D_MODEL + h * HD;
  union st8 { uint2 u2; __hip_bfloat162 h2[2]; };
#pragma unroll
  for (int gg = 0; gg < 4; ++gg) {
    st8 o0, o1;
    o0.h2[0] = __float22bfloat162_rn(make_float2(acc0[4 * gg + 0] * inv, acc0[4 * gg + 1] * inv));
    o0.h2[1] = __float22bfloat162_rn(make_float2(acc0[4 * gg + 2] * inv, acc0[4 * gg + 3] * inv));
    o1.h2[0] = __float22bfloat162_rn(make_float2(acc1[4 * gg + 0] * inv, acc1[4 * gg + 1] * inv));
    o1.h2[1] = __float22bfloat162_rn(make_float2(acc1[4 * gg + 2] * inv, acc1[4 * gg + 3] * inv));
    *(uint2*)(yrow + 8 * gg + 4 * hi)      = o0.u2;
    *(uint2*)(yrow + 32 + 8 * gg + 4 * hi) = o1.u2;
  }
}

// ---------------------------------------------------------------------------
extern "C" void kernel_launch(void* const* d_in, const int* in_sizes, int n_in,
                              void* d_out, int out_size, void* d_ws,
                              size_t ws_size, hipStream_t stream) {
  const float* x    = (const float*)d_in[0];
  const float* cosb = (const float*)d_in[1];
  const float* sinb = (const float*)d_in[2];
  const float* Wq   = (const float*)d_in[3];
  const float* Wk   = (const float*)d_in[4];
  const float* Wv   = (const float*)d_in[5];
  const float* Wo   = (const float*)d_in[6];
  const float* qs   = (const float*)d_in[7];
  const float* ks   = (const float*)d_in[8];
  float* out = (float*)d_out;   // reference output dtype is float32

  char* ws = (char*)d_ws;
  bf16_t* qkv = (bf16_t*)ws;                                   // 25165824 B
  bf16_t* v_t = (bf16_t*)(ws + 25165824);                      // 4194304 B
  bf16_t* y   = (bf16_t*)(ws + 25165824 + 4194304);            // 16777216 B

  gemm_bt<true, bf16_t><<<dim3(12, 64), 256, 0, stream>>>(x, Wq, Wk, Wv, qkv, LDQKV);
  rms_rope<<<dim3(8192), 256, 0, stream>>>(qkv, cosb, sinb, qs, ks);
  v_transpose<<<dim3(16, 32), 256, 0, stream>>>(qkv, v_t);
  attn<<<dim3(1024), 256, 0, stream>>>(qkv, v_t, y);
  gemm_bt<false, float><<<dim3(8, 64), 256, 0, stream>>>(y, Wo, Wo, Wo, out, D_MODEL);
}

// Round 10
// 199.773 us; speedup vs baseline: 1.1860x; 1.1860x over previous
//
#include <hip/hip_runtime.h>
#include <hip/hip_bf16.h>
#include <stdint.h>

typedef __attribute__((ext_vector_type(8)))  __bf16 bf16x8;
typedef __attribute__((ext_vector_type(4)))  float  f32x4;
typedef __attribute__((ext_vector_type(16))) float  f32x16;
typedef __hip_bfloat16 bf16_t;

#define T_SEQ 2048
#define D_MODEL 1024
#define N_HEADS 16
#define N_KV 4
#define HD 64
#define LDQKV 1536
#define KDIM 1024

// Convert 16 consecutive fp32 (4x float4) -> 16 bf16 (2x int4)
__device__ inline void cvt16(const float4* __restrict__ g, int4* __restrict__ s) {
  float4 v0 = g[0], v1 = g[1], v2 = g[2], v3 = g[3];
  union { int4 i[2]; __hip_bfloat162 h[8]; } u;
  u.h[0] = __float22bfloat162_rn(make_float2(v0.x, v0.y));
  u.h[1] = __float22bfloat162_rn(make_float2(v0.z, v0.w));
  u.h[2] = __float22bfloat162_rn(make_float2(v1.x, v1.y));
  u.h[3] = __float22bfloat162_rn(make_float2(v1.z, v1.w));
  u.h[4] = __float22bfloat162_rn(make_float2(v2.x, v2.y));
  u.h[5] = __float22bfloat162_rn(make_float2(v2.z, v2.w));
  u.h[6] = __float22bfloat162_rn(make_float2(v3.x, v3.y));
  u.h[7] = __float22bfloat162_rn(make_float2(v3.z, v3.w));
  s[0] = u.i[0]; s[1] = u.i[1];
}

__device__ inline void storeC(bf16_t* p, float v) { *p = __float2bfloat16(v); }
__device__ inline void storeC(float* p, float v) { *p = v; }

// v_permlane32_swap_b32 vdst, vsrc: after plswap(a,b): a={a_L,b_L}, b={a_U,b_U}
__device__ inline void plswap(unsigned& a, unsigned& b) {
  asm volatile("v_permlane32_swap_b32 %0, %1" : "+v"(a), "+v"(b));
}

// async global->LDS, 16B per lane; lds dest must be wave-uniform base.
__device__ inline void gll16(const bf16_t* g, bf16_t* l) {
  __builtin_amdgcn_global_load_lds(
      (const __attribute__((address_space(1))) void*)g,
      (__attribute__((address_space(3))) void*)l, 16, 0, 0);
}

// ---------------------------------------------------------------------------
// fp32 -> bf16 bulk convert: thread i handles 16 elements.
// ---------------------------------------------------------------------------
__global__ __launch_bounds__(256) void to_bf16(const float* __restrict__ s,
                                               bf16_t* __restrict__ d,
                                               const int n16) {
  const int i = blockIdx.x * 256 + threadIdx.x;
  if (i < n16) cvt16((const float4*)s + i * 4, (int4*)d + i * 2);
}

// ---------------------------------------------------------------------------
// GEMM bf16 x bf16: C[m0+row, n0+col] = sum_k A[m0+row,k] * W[n0+col,k]
// m97 structure: 128x128 tile, BK=32, global_load_lds w16 staging (linear
// LDS), 4 waves (2x2), 4x4 16x16x32 MFMA frags/wave.
// ---------------------------------------------------------------------------
template <typename CT>
__global__ __launch_bounds__(256) void gemm_bb(
    const bf16_t* __restrict__ A, const bf16_t* __restrict__ W,
    CT* __restrict__ C, const int ldC)
{
  __shared__ bf16_t As[128 * 32];
  __shared__ bf16_t Bs[128 * 32];
  const int tid = threadIdx.x;
  const int lane = tid & 63;
  const int wv = tid >> 6;
  const int wr = wv >> 1, wc = wv & 1;
  const int m0 = blockIdx.y * 128;
  const int n0 = blockIdx.x * 128;

  // staging: wave wv fills tile rows 32wv..32wv+31; 2 gll calls per side.
  const int srow = lane >> 2;          // 0..15 within a call
  const int scol = (lane & 3) * 8;     // bf16 col offset
  const bf16_t* gA = A + (size_t)(m0 + 32 * wv + srow) * KDIM + scol;
  const bf16_t* gB = W + (size_t)(n0 + 32 * wv + srow) * KDIM + scol;
  bf16_t* lA = As + wv * 1024;         // wave-uniform LDS bases
  bf16_t* lB = Bs + wv * 1024;

  f32x4 acc[4][4];
#pragma unroll
  for (int m = 0; m < 4; ++m)
#pragma unroll
    for (int n = 0; n < 4; ++n)
      acc[m][n] = {0.f, 0.f, 0.f, 0.f};

  const int fr = lane & 15;
  const int fq = lane >> 4;

  for (int k0 = 0; k0 < KDIM; k0 += 32) {
    gll16(gA + k0, lA);
    gll16(gA + 16 * KDIM + k0, lA + 512);
    gll16(gB + k0, lB);
    gll16(gB + 16 * KDIM + k0, lB + 512);
    __syncthreads();
    bf16x8 af[4], bfv[4];
#pragma unroll
    for (int m = 0; m < 4; ++m)
      af[m] = *(const bf16x8*)(&As[(wr * 64 + m * 16 + fr) * 32 + fq * 8]);
#pragma unroll
    for (int n = 0; n < 4; ++n)
      bfv[n] = *(const bf16x8*)(&Bs[(wc * 64 + n * 16 + fr) * 32 + fq * 8]);
#pragma unroll
    for (int m = 0; m < 4; ++m)
#pragma unroll
      for (int n = 0; n < 4; ++n)
        acc[m][n] = __builtin_amdgcn_mfma_f32_16x16x32_bf16(af[m], bfv[n],
                                                            acc[m][n], 0, 0, 0);
    __syncthreads();
  }

#pragma unroll
  for (int m = 0; m < 4; ++m)
#pragma unroll
    for (int n = 0; n < 4; ++n)
#pragma unroll
      for (int r = 0; r < 4; ++r) {
        const int row = wr * 64 + m * 16 + fq * 4 + r;
        const int col = wc * 64 + n * 16 + fr;
        storeC(&C[(size_t)(m0 + row) * ldC + n0 + col], acc[m][n][r]);
      }
}

// ---------------------------------------------------------------------------
// RMSNorm + RoPE (unchanged — passing)
// ---------------------------------------------------------------------------
__global__ __launch_bounds__(256) void rms_rope(
    bf16_t* __restrict__ qkv, const float* __restrict__ cosb,
    const float* __restrict__ sinb, const float* __restrict__ qs,
    const float* __restrict__ ks)
{
  const int row = blockIdx.x;
  const int t = row & (T_SEQ - 1);
  const int tid = threadIdx.x;
  const int lane = tid & 63;
  const int wv = tid >> 6;
  const int f = lane & 15;
  const float c = (lane < 32) ? cosb[t * 16 + f] : 0.f;
  const float s = (lane < 32) ? sinb[t * 16 + f] : 0.f;
  for (int hh = wv; hh < 20; hh += 4) {
    const size_t idx = (size_t)row * LDQKV + hh * 64 + lane;
    const float v = __bfloat162float(qkv[idx]);
    float ssum = v * v;
#pragma unroll
    for (int off = 32; off; off >>= 1) ssum += __shfl_xor(ssum, off);
    const float norm = rsqrtf(ssum * (1.f / 64.f) + 1e-6f);
    const float scale = (hh < 16 ? qs : ks)[lane];
    float val = v * norm * scale;
    const float partner = __shfl_xor(val, 16);
    if (lane < 16)      val = val * c - partner * s;
    else if (lane < 32) val = partner * s + val * c;
    qkv[idx] = __float2bfloat16(val);
  }
}

// ---------------------------------------------------------------------------
// V transpose (unchanged — passing)
// ---------------------------------------------------------------------------
__global__ __launch_bounds__(256) void v_transpose(
    const bf16_t* __restrict__ qkv, bf16_t* __restrict__ v_t)
{
  __shared__ bf16_t tile[64 * 72];
  const int g = blockIdx.x;
  const int t0 = blockIdx.y * 64;
  const int tid = threadIdx.x;
  const int i = tid >> 2;
  const int dc = (tid & 3) * 16;
  const bf16_t* src = qkv + (size_t)((g >> 2) * T_SEQ + t0 + i) * LDQKV
                      + 1280 + (g & 3) * HD + dc;
  const int4* gs = (const int4*)src;
  int4 x0 = gs[0], x1 = gs[1];
  int4* st = (int4*)(&tile[i * 72 + dc]);
  st[0] = x0; st[1] = x1;
  __syncthreads();
  union { int4 v[2]; bf16_t h[16]; } u;
#pragma unroll
  for (int j = 0; j < 16; ++j) u.h[j] = tile[(dc + j) * 72 + i];
  int4* dst = (int4*)(v_t + (size_t)(g * HD + i) * T_SEQ + t0 + dc);
  dst[0] = u.v[0]; dst[1] = u.v[1];
}

// ---------------------------------------------------------------------------
// Causal GQA flash attention v7 — v6 plus: CU-balanced sb permutation (each
// CU residue class sums to 30 strip-blocks), const-zero MFMA C operand (no
// per-tile st zeroing), in-place masking (no sreg copy), max3-shaped trees.
// ---------------------------------------------------------------------------
__global__ __launch_bounds__(256) void attn(
    const bf16_t* __restrict__ qkv, const bf16_t* __restrict__ v_t,
    bf16_t* __restrict__ y)
{
  __shared__ int4 lds[1024];      // 16 KB: dbuf x (K 4KB + V 4KB)
  const int tid  = threadIdx.x;
  const int lane = tid & 63;
  const int wv   = tid >> 6;
  const int ql   = lane & 31;      // q within strip; also d_local for V frags
  const int hi   = lane >> 5;      // half-wave index
  const int id   = (int)blockIdx.x;          // 0..1023
  const int low3 = id & 7;
  const int rest = id >> 3;                  // 0..127
  const int gsel = rest & 1;
  const int hh   = (rest >> 1) & 3;
  const int sbi  = rest >> 3;                // 0..15
  // balanced permutation: CU class {m,m+4,m+8,m+12} -> sb sums of 30 each.
  // sbi 0..3 -> 15-sbi; 4..7 -> sbi+4; 8..11 -> 15-sbi; 12..15 -> sbi-12
  const int sb   = ((sbi >> 2) & 1) ? (sbi + 4 - ((sbi >> 3) << 4)) : (15 - sbi);
  const int g16  = low3 + 8 * gsel;          // b*4+kvh
  const int b    = g16 >> 2, kvh = g16 & 3;
  const int h    = kvh * 4 + hh;
  const int s    = sb * 4 + wv;              // this wave's strip 0..63
  const int q_glob = s * 32 + ql;
  const int nt     = s + 1;                  // wave's tiles (last = diagonal)
  const int ntmax  = sb * 4 + 4;             // block-uniform staging count
  const float SCALE_LOG2 = 0.125f * 1.44269504089f;  // 1/sqrt(64)*log2(e)

  // --- per-thread staging addresses (tile-relative) ---
  const int kr = tid >> 3, kslot = tid & 7;          // K: row 0..31, 16B slot
  const int vd = tid >> 2, vslot = tid & 3;          // V: d-row 0..63, slot
  const bf16_t* gK = qkv + (size_t)(b * T_SEQ + kr) * LDQKV + 1024 + kvh * HD + kslot * 8;
  const bf16_t* gV = v_t + (size_t)((b * N_KV + kvh) * HD + vd) * T_SEQ + vslot * 8;
  const int wKidx = kr * 8 + (kslot ^ (kr & 7));
  const int wVidx = 256 + vd * 4 + (vslot ^ ((vd >> 1) & 3));

  // --- per-lane fragment read indices (tile-relative, int4 units) ---
  int kridx[4];
#pragma unroll
  for (int c = 0; c < 4; ++c)
    kridx[c] = ql * 8 + ((2 * c + hi) ^ (ql & 7));
  const int vsw = (ql >> 1) & 3;
  const int v0idx = 256 + ql * 4 + (hi ^ vsw);
  const int v1idx = 256 + ql * 4 + ((2 + hi) ^ vsw);
  const int v2idx = 256 + (ql + 32) * 4 + (hi ^ vsw);
  const int v3idx = 256 + (ql + 32) * 4 + ((2 + hi) ^ vsw);

  // Q fragments (B-operand), pre-scaled into log2 domain
  const bf16_t* Qrow = qkv + (size_t)(b * T_SEQ + q_glob) * LDQKV + h * HD + hi * 8;
  bf16x8 qfrag[4];
#pragma unroll
  for (int c = 0; c < 4; ++c) {
    bf16x8 raw = *(const bf16x8*)(Qrow + c * 16);
    bf16x8 sc;
#pragma unroll
    for (int j = 0; j < 8; ++j)
      sc[j] = (__bf16)((float)raw[j] * SCALE_LOG2);
    qfrag[c] = sc;
  }

  f32x16 acc0, acc1, zro;
#pragma unroll
  for (int i = 0; i < 16; ++i) { acc0[i] = 0.f; acc1[i] = 0.f; zro[i] = 0.f; }
  float m_run = -1e30f, l_run = 0.f;

  // prologue: stage tile 0 into buf 0
  {
    int4 kreg = *(const int4*)gK;
    int4 vreg = *(const int4*)gV;
    lds[wKidx] = kreg;
    lds[wVidx] = vreg;
  }
  __syncthreads();

  int buf = 0;
  for (int t = 0; t < ntmax; ++t) {
    // issue next tile's staging loads early (latency hides under compute)
    int4 kreg, vreg;
    const bool more = (t + 1 < ntmax);
    if (more) {
      kreg = *(const int4*)(gK + (size_t)(t + 1) * 32 * LDQKV);
      vreg = *(const int4*)(gV + (t + 1) * 32);
    }

    if (t < nt) {
      const int k0 = t << 5;
      const bool masked = (t == nt - 1);
      const int base = buf * 512;

      bf16x8 kf0 = *(const bf16x8*)&lds[base + kridx[0]];
      bf16x8 kf1 = *(const bf16x8*)&lds[base + kridx[1]];
      bf16x8 kf2 = *(const bf16x8*)&lds[base + kridx[2]];
      bf16x8 kf3 = *(const bf16x8*)&lds[base + kridx[3]];

      // QK^T in log2 domain; C-in = const zero regs (no per-tile zeroing)
      f32x16 st = __builtin_amdgcn_mfma_f32_32x32x16_bf16(kf0, qfrag[0], zro, 0, 0, 0);
      st = __builtin_amdgcn_mfma_f32_32x32x16_bf16(kf1, qfrag[1], st, 0, 0, 0);
      st = __builtin_amdgcn_mfma_f32_32x32x16_bf16(kf2, qfrag[2], st, 0, 0, 0);
      st = __builtin_amdgcn_mfma_f32_32x32x16_bf16(kf3, qfrag[3], st, 0, 0, 0);

      // softmax, in-register, log2 domain, in-place on st
      if (masked) {
#pragma unroll
        for (int rr = 0; rr < 16; ++rr) {
          const int kg = k0 + (rr & 3) + 8 * (rr >> 2) + 4 * hi;
          if (kg > q_glob) st[rr] = -1e30f;
        }
      }
      // max3-shaped tree (15 values -> 8 instrs when fused)
      float m01 = fmaxf(fmaxf(st[0], st[1]), st[2]);
      float m02 = fmaxf(fmaxf(st[3], st[4]), st[5]);
      float m03 = fmaxf(fmaxf(st[6], st[7]), st[8]);
      float m04 = fmaxf(fmaxf(st[9], st[10]), st[11]);
      float m05 = fmaxf(fmaxf(st[12], st[13]), st[14]);
      float m06 = fmaxf(fmaxf(m01, m02), m03);
      float m07 = fmaxf(fmaxf(m04, m05), st[15]);
      const float bmax = fmaxf(m06, m07);
      if (__any(bmax > m_run + 8.f)) {        // T13 defer-max
        const float rmax = fmaxf(bmax, __shfl_xor(bmax, 32));
        const float mnew = fmaxf(m_run, rmax);
        const float corr = exp2f(m_run - mnew);
#pragma unroll
        for (int i = 0; i < 16; ++i) { acc0[i] *= corr; acc1[i] *= corr; }
        l_run *= corr;
        m_run = mnew;
      }
      float pp[16];
#pragma unroll
      for (int rr = 0; rr < 16; ++rr) pp[rr] = exp2f(st[rr] - m_run);
      float l01 = (pp[0] + pp[1]) + (pp[2] + pp[3]);
      float l02 = (pp[4] + pp[5]) + (pp[6] + pp[7]);
      float l03 = (pp[8] + pp[9]) + (pp[10] + pp[11]);
      float l04 = (pp[12] + pp[13]) + (pp[14] + pp[15]);
      float lsum = (l01 + l02) + (l03 + l04);
      lsum += __shfl_xor(lsum, 32);
      l_run += lsum;

      // pack P^T B-fragments via permlane32_swap
      union pk { __hip_bfloat162 h2; unsigned u; };
      unsigned w[8];
#pragma unroll
      for (int i = 0; i < 8; ++i) {
        pk t2; t2.h2 = __float22bfloat162_rn(make_float2(pp[2 * i], pp[2 * i + 1]));
        w[i] = t2.u;
      }
      plswap(w[0], w[2]); plswap(w[1], w[3]);
      plswap(w[4], w[6]); plswap(w[5], w[7]);
      union fu { unsigned u[4]; bf16x8 v; };
      fu f1, f2;
      f1.u[0] = w[0]; f1.u[1] = w[1]; f1.u[2] = w[2]; f1.u[3] = w[3];
      f2.u[0] = w[4]; f2.u[1] = w[5]; f2.u[2] = w[6]; f2.u[3] = w[7];

      bf16x8 vf0 = *(const bf16x8*)&lds[base + v0idx];
      bf16x8 vf1 = *(const bf16x8*)&lds[base + v1idx];
      bf16x8 vf2 = *(const bf16x8*)&lds[base + v2idx];
      bf16x8 vf3 = *(const bf16x8*)&lds[base + v3idx];

      acc0 = __builtin_amdgcn_mfma_f32_32x32x16_bf16(vf0, f1.v, acc0, 0, 0, 0);
      acc0 = __builtin_amdgcn_mfma_f32_32x32x16_bf16(vf1, f2.v, acc0, 0, 0, 0);
      acc1 = __builtin_amdgcn_mfma_f32_32x32x16_bf16(vf2, f1.v, acc1, 0, 0, 0);
      acc1 = __builtin_amdgcn_mfma_f32_32x32x16_bf16(vf3, f2.v, acc1, 0, 0, 0);
    }

    // write next tile into the other buffer (prev readers fenced by the
    // barrier at the end of the previous iteration)
    if (more) {
      const int nb = (buf ^ 1) * 512;
      lds[nb + wKidx] = kreg;
      lds[nb + wVidx] = vreg;
    }
    __syncthreads();
    buf ^= 1;
  }

  // epilogue: O = acc / l_run
  const float inv = 1.f / l_run;
  bf16_t* yrow = y + (size_t)(b * T_SEQ + q_glob) * D_MODEL + h * HD;
  union st8 { uint2 u2; __hip_bfloat162 h2[2]; };
#pragma unroll
  for (int gg = 0; gg < 4; ++gg) {
    st8 o0, o1;
    o0.h2[0] = __float22bfloat162_rn(make_float2(acc0[4 * gg + 0] * inv, acc0[4 * gg + 1] * inv));
    o0.h2[1] = __float22bfloat162_rn(make_float2(acc0[4 * gg + 2] * inv, acc0[4 * gg + 3] * inv));
    o1.h2[0] = __float22bfloat162_rn(make_float2(acc1[4 * gg + 0] * inv, acc1[4 * gg + 1] * inv));
    o1.h2[1] = __float22bfloat162_rn(make_float2(acc1[4 * gg + 2] * inv, acc1[4 * gg + 3] * inv));
    *(uint2*)(yrow + 8 * gg + 4 * hi)      = o0.u2;
    *(uint2*)(yrow + 32 + 8 * gg + 4 * hi) = o1.u2;
  }
}

// ---------------------------------------------------------------------------
extern "C" void kernel_launch(void* const* d_in, const int* in_sizes, int n_in,
                              void* d_out, int out_size, void* d_ws,
                              size_t ws_size, hipStream_t stream) {
  const float* x    = (const float*)d_in[0];
  const float* cosb = (const float*)d_in[1];
  const float* sinb = (const float*)d_in[2];
  const float* Wq   = (const float*)d_in[3];
  const float* Wk   = (const float*)d_in[4];
  const float* Wv   = (const float*)d_in[5];
  const float* Wo   = (const float*)d_in[6];
  const float* qs   = (const float*)d_in[7];
  const float* ks   = (const float*)d_in[8];
  float* out = (float*)d_out;   // reference output dtype is float32

  char* ws = (char*)d_ws;
  bf16_t* qkv   = (bf16_t*)ws;                       // 25165824 B
  bf16_t* v_t   = (bf16_t*)(ws + 25165824);          // 4194304 B
  bf16_t* y     = (bf16_t*)(ws + 29360128);          // 16777216 B (= xb alias)
  bf16_t* xb    = y;                                 // xb dead before attn writes y
  bf16_t* wqkvb = (bf16_t*)(ws + 46137344);          // 3145728 B
  bf16_t* wob   = (bf16_t*)(ws + 49283072);          // 2097152 B  (total ~51.4 MB)

  // 0. one-time fp32 -> bf16 conversions
  to_bf16<<<dim3(2048), 256, 0, stream>>>(x, xb, 524288);
  to_bf16<<<dim3(256),  256, 0, stream>>>(Wq, wqkvb, 65536);
  to_bf16<<<dim3(64),   256, 0, stream>>>(Wk, wqkvb + 1024 * 1024, 16384);
  to_bf16<<<dim3(64),   256, 0, stream>>>(Wv, wqkvb + 1280 * 1024, 16384);
  to_bf16<<<dim3(256),  256, 0, stream>>>(Wo, wob, 65536);

  // 1. fused QKV projection (bf16 x bf16, global_load_lds staging)
  gemm_bb<bf16_t><<<dim3(12, 64), 256, 0, stream>>>(xb, wqkvb, qkv, LDQKV);
  // 2. RMSNorm + RoPE in-place on q,k
  rms_rope<<<dim3(8192), 256, 0, stream>>>(qkv, cosb, sinb, qs, ks);
  // 3. V transpose
  v_transpose<<<dim3(16, 32), 256, 0, stream>>>(qkv, v_t);
  // 4. causal GQA flash attention -> y (overwrites xb, which is dead now)
  attn<<<dim3(1024), 256, 0, stream>>>(qkv, v_t, y);
  // 5. output projection (bf16 x bf16 -> fp32)
  gemm_bb<float><<<dim3(8, 64), 256, 0, stream>>>(y, wob, out, D_MODEL);
}

// Round 11
// 184.798 us; speedup vs baseline: 1.2821x; 1.0810x over previous
//
#include <hip/hip_runtime.h>
#include <hip/hip_bf16.h>
#include <stdint.h>

typedef __attribute__((ext_vector_type(8)))  __bf16 bf16x8;
typedef __attribute__((ext_vector_type(4)))  float  f32x4;
typedef __attribute__((ext_vector_type(16))) float  f32x16;
typedef __hip_bfloat16 bf16_t;

#define T_SEQ 2048
#define D_MODEL 1024
#define N_HEADS 16
#define N_KV 4
#define HD 64
#define LDQKV 1536
#define KDIM 1024

// Convert 16 consecutive fp32 (4x float4) -> 16 bf16 (2x int4)
__device__ inline void cvt16(const float4* __restrict__ g, int4* __restrict__ s) {
  float4 v0 = g[0], v1 = g[1], v2 = g[2], v3 = g[3];
  union { int4 i[2]; __hip_bfloat162 h[8]; } u;
  u.h[0] = __float22bfloat162_rn(make_float2(v0.x, v0.y));
  u.h[1] = __float22bfloat162_rn(make_float2(v0.z, v0.w));
  u.h[2] = __float22bfloat162_rn(make_float2(v1.x, v1.y));
  u.h[3] = __float22bfloat162_rn(make_float2(v1.z, v1.w));
  u.h[4] = __float22bfloat162_rn(make_float2(v2.x, v2.y));
  u.h[5] = __float22bfloat162_rn(make_float2(v2.z, v2.w));
  u.h[6] = __float22bfloat162_rn(make_float2(v3.x, v3.y));
  u.h[7] = __float22bfloat162_rn(make_float2(v3.z, v3.w));
  s[0] = u.i[0]; s[1] = u.i[1];
}

__device__ inline void storeC(bf16_t* p, float v) { *p = __float2bfloat16(v); }
__device__ inline void storeC(float* p, float v) { *p = v; }

// v_permlane32_swap_b32 vdst, vsrc: after plswap(a,b): a={a_L,b_L}, b={a_U,b_U}
__device__ inline void plswap(unsigned& a, unsigned& b) {
  asm volatile("v_permlane32_swap_b32 %0, %1" : "+v"(a), "+v"(b));
}

// HW transcendental exp2 (input already in log2 domain)
__device__ inline float fexp2(float x) {
  float r; asm("v_exp_f32 %0, %1" : "=v"(r) : "v"(x)); return r;
}
// HW packed fp32->bf16 (T12 recipe; no builtin on gfx950)
__device__ inline unsigned cvtpk(float lo, float hi) {
  unsigned r; asm("v_cvt_pk_bf16_f32 %0, %1, %2" : "=v"(r) : "v"(lo), "v"(hi));
  return r;
}

// async global->LDS, 16B per lane; lds dest must be wave-uniform base.
__device__ inline void gll16(const bf16_t* g, bf16_t* l) {
  __builtin_amdgcn_global_load_lds(
      (const __attribute__((address_space(1))) void*)g,
      (__attribute__((address_space(3))) void*)l, 16, 0, 0);
}

// ---------------------------------------------------------------------------
// fp32 -> bf16 bulk convert: thread i handles 16 elements.
// ---------------------------------------------------------------------------
__global__ __launch_bounds__(256) void to_bf16(const float* __restrict__ s,
                                               bf16_t* __restrict__ d,
                                               const int n16) {
  const int i = blockIdx.x * 256 + threadIdx.x;
  if (i < n16) cvt16((const float4*)s + i * 4, (int4*)d + i * 2);
}

// ---------------------------------------------------------------------------
// GEMM bf16 x bf16 (unchanged from round 10 — passing)
// ---------------------------------------------------------------------------
template <typename CT>
__global__ __launch_bounds__(256) void gemm_bb(
    const bf16_t* __restrict__ A, const bf16_t* __restrict__ W,
    CT* __restrict__ C, const int ldC)
{
  __shared__ bf16_t As[128 * 32];
  __shared__ bf16_t Bs[128 * 32];
  const int tid = threadIdx.x;
  const int lane = tid & 63;
  const int wv = tid >> 6;
  const int wr = wv >> 1, wc = wv & 1;
  const int m0 = blockIdx.y * 128;
  const int n0 = blockIdx.x * 128;

  const int srow = lane >> 2;
  const int scol = (lane & 3) * 8;
  const bf16_t* gA = A + (size_t)(m0 + 32 * wv + srow) * KDIM + scol;
  const bf16_t* gB = W + (size_t)(n0 + 32 * wv + srow) * KDIM + scol;
  bf16_t* lA = As + wv * 1024;
  bf16_t* lB = Bs + wv * 1024;

  f32x4 acc[4][4];
#pragma unroll
  for (int m = 0; m < 4; ++m)
#pragma unroll
    for (int n = 0; n < 4; ++n)
      acc[m][n] = {0.f, 0.f, 0.f, 0.f};

  const int fr = lane & 15;
  const int fq = lane >> 4;

  for (int k0 = 0; k0 < KDIM; k0 += 32) {
    gll16(gA + k0, lA);
    gll16(gA + 16 * KDIM + k0, lA + 512);
    gll16(gB + k0, lB);
    gll16(gB + 16 * KDIM + k0, lB + 512);
    __syncthreads();
    bf16x8 af[4], bfv[4];
#pragma unroll
    for (int m = 0; m < 4; ++m)
      af[m] = *(const bf16x8*)(&As[(wr * 64 + m * 16 + fr) * 32 + fq * 8]);
#pragma unroll
    for (int n = 0; n < 4; ++n)
      bfv[n] = *(const bf16x8*)(&Bs[(wc * 64 + n * 16 + fr) * 32 + fq * 8]);
#pragma unroll
    for (int m = 0; m < 4; ++m)
#pragma unroll
      for (int n = 0; n < 4; ++n)
        acc[m][n] = __builtin_amdgcn_mfma_f32_16x16x32_bf16(af[m], bfv[n],
                                                            acc[m][n], 0, 0, 0);
    __syncthreads();
  }

#pragma unroll
  for (int m = 0; m < 4; ++m)
#pragma unroll
    for (int n = 0; n < 4; ++n)
#pragma unroll
      for (int r = 0; r < 4; ++r) {
        const int row = wr * 64 + m * 16 + fq * 4 + r;
        const int col = wc * 64 + n * 16 + fr;
        storeC(&C[(size_t)(m0 + row) * ldC + n0 + col], acc[m][n][r]);
      }
}

// ---------------------------------------------------------------------------
// RMSNorm + RoPE (unchanged — passing)
// ---------------------------------------------------------------------------
__global__ __launch_bounds__(256) void rms_rope(
    bf16_t* __restrict__ qkv, const float* __restrict__ cosb,
    const float* __restrict__ sinb, const float* __restrict__ qs,
    const float* __restrict__ ks)
{
  const int row = blockIdx.x;
  const int t = row & (T_SEQ - 1);
  const int tid = threadIdx.x;
  const int lane = tid & 63;
  const int wv = tid >> 6;
  const int f = lane & 15;
  const float c = (lane < 32) ? cosb[t * 16 + f] : 0.f;
  const float s = (lane < 32) ? sinb[t * 16 + f] : 0.f;
  for (int hh = wv; hh < 20; hh += 4) {
    const size_t idx = (size_t)row * LDQKV + hh * 64 + lane;
    const float v = __bfloat162float(qkv[idx]);
    float ssum = v * v;
#pragma unroll
    for (int off = 32; off; off >>= 1) ssum += __shfl_xor(ssum, off);
    const float norm = rsqrtf(ssum * (1.f / 64.f) + 1e-6f);
    const float scale = (hh < 16 ? qs : ks)[lane];
    float val = v * norm * scale;
    const float partner = __shfl_xor(val, 16);
    if (lane < 16)      val = val * c - partner * s;
    else if (lane < 32) val = partner * s + val * c;
    qkv[idx] = __float2bfloat16(val);
  }
}

// ---------------------------------------------------------------------------
// V transpose (unchanged — passing)
// ---------------------------------------------------------------------------
__global__ __launch_bounds__(256) void v_transpose(
    const bf16_t* __restrict__ qkv, bf16_t* __restrict__ v_t)
{
  __shared__ bf16_t tile[64 * 72];
  const int g = blockIdx.x;
  const int t0 = blockIdx.y * 64;
  const int tid = threadIdx.x;
  const int i = tid >> 2;
  const int dc = (tid & 3) * 16;
  const bf16_t* src = qkv + (size_t)((g >> 2) * T_SEQ + t0 + i) * LDQKV
                      + 1280 + (g & 3) * HD + dc;
  const int4* gs = (const int4*)src;
  int4 x0 = gs[0], x1 = gs[1];
  int4* st = (int4*)(&tile[i * 72 + dc]);
  st[0] = x0; st[1] = x1;
  __syncthreads();
  union { int4 v[2]; bf16_t h[16]; } u;
#pragma unroll
  for (int j = 0; j < 16; ++j) u.h[j] = tile[(dc + j) * 72 + i];
  int4* dst = (int4*)(v_t + (size_t)(g * HD + i) * T_SEQ + t0 + dc);
  dst[0] = u.v[0]; dst[1] = u.v[1];
}

// ---------------------------------------------------------------------------
// Causal GQA flash attention v8 — v7 plus VALU-diet:
//  * v_cvt_pk_bf16_f32 inline asm for P-pack + epilogue (T12)
//  * v_exp_f32 inline asm for exp2 (args already log2-domain)
//  * row-sum l folded into matrix pipe: accL = mfma(ones, P) so accL[0]
//    tracks l with the same corr rescaling; kills sum-tree + shfl.
//  * staging pointers incremented, not recomputed.
// ---------------------------------------------------------------------------
__global__ __launch_bounds__(256) void attn(
    const bf16_t* __restrict__ qkv, const bf16_t* __restrict__ v_t,
    bf16_t* __restrict__ y)
{
  __shared__ int4 lds[1024];      // 16 KB: dbuf x (K 4KB + V 4KB)
  const int tid  = threadIdx.x;
  const int lane = tid & 63;
  const int wv   = tid >> 6;
  const int ql   = lane & 31;
  const int hi   = lane >> 5;
  const int id   = (int)blockIdx.x;          // 0..1023
  const int low3 = id & 7;
  const int rest = id >> 3;
  const int gsel = rest & 1;
  const int hh   = (rest >> 1) & 3;
  const int sbi  = rest >> 3;                // 0..15
  const int sb   = ((sbi >> 2) & 1) ? (sbi + 4 - ((sbi >> 3) << 4)) : (15 - sbi);
  const int g16  = low3 + 8 * gsel;          // b*4+kvh
  const int b    = g16 >> 2, kvh = g16 & 3;
  const int h    = kvh * 4 + hh;
  const int s    = sb * 4 + wv;
  const int q_glob = s * 32 + ql;
  const int nt     = s + 1;
  const int ntmax  = sb * 4 + 4;
  const float SCALE_LOG2 = 0.125f * 1.44269504089f;

  // staging addresses
  const int kr = tid >> 3, kslot = tid & 7;
  const int vd = tid >> 2, vslot = tid & 3;
  const bf16_t* gK = qkv + (size_t)(b * T_SEQ + kr) * LDQKV + 1024 + kvh * HD + kslot * 8;
  const bf16_t* gV = v_t + (size_t)((b * N_KV + kvh) * HD + vd) * T_SEQ + vslot * 8;
  const int wKidx = kr * 8 + (kslot ^ (kr & 7));
  const int wVidx = 256 + vd * 4 + (vslot ^ ((vd >> 1) & 3));

  // fragment read indices
  int kridx[4];
#pragma unroll
  for (int c = 0; c < 4; ++c)
    kridx[c] = ql * 8 + ((2 * c + hi) ^ (ql & 7));
  const int vsw = (ql >> 1) & 3;
  const int v0idx = 256 + ql * 4 + (hi ^ vsw);
  const int v1idx = 256 + ql * 4 + ((2 + hi) ^ vsw);
  const int v2idx = 256 + (ql + 32) * 4 + (hi ^ vsw);
  const int v3idx = 256 + (ql + 32) * 4 + ((2 + hi) ^ vsw);

  // Q fragments, pre-scaled into log2 domain
  const bf16_t* Qrow = qkv + (size_t)(b * T_SEQ + q_glob) * LDQKV + h * HD + hi * 8;
  bf16x8 qfrag[4];
#pragma unroll
  for (int c = 0; c < 4; ++c) {
    bf16x8 raw = *(const bf16x8*)(Qrow + c * 16);
    bf16x8 sc;
#pragma unroll
    for (int j = 0; j < 8; ++j)
      sc[j] = (__bf16)((float)raw[j] * SCALE_LOG2);
    qfrag[c] = sc;
  }

  // all-ones A fragment for the l-row MFMA
  union ob { unsigned u[4]; bf16x8 v; } onesf;
#pragma unroll
  for (int i = 0; i < 4; ++i) onesf.u[i] = 0x3F803F80u;

  f32x16 acc0, acc1, accL, zro;
#pragma unroll
  for (int i = 0; i < 16; ++i) { acc0[i] = 0.f; acc1[i] = 0.f; accL[i] = 0.f; zro[i] = 0.f; }
  float m_run = -1e30f;

  // prologue: stage tile 0 into buf 0
  {
    int4 kreg = *(const int4*)gK;
    int4 vreg = *(const int4*)gV;
    lds[wKidx] = kreg;
    lds[wVidx] = vreg;
  }
  __syncthreads();

  const bf16_t* pKn = gK + (size_t)32 * LDQKV;   // next-tile staging pointers
  const bf16_t* pVn = gV + 32;

  int buf = 0;
  for (int t = 0; t < ntmax; ++t) {
    int4 kreg, vreg;
    const bool more = (t + 1 < ntmax);
    if (more) {
      kreg = *(const int4*)pKn;
      vreg = *(const int4*)pVn;
    }

    if (t < nt) {
      const int k0 = t << 5;
      const bool masked = (t == nt - 1);
      const int base = buf * 512;

      bf16x8 kf0 = *(const bf16x8*)&lds[base + kridx[0]];
      bf16x8 kf1 = *(const bf16x8*)&lds[base + kridx[1]];
      bf16x8 kf2 = *(const bf16x8*)&lds[base + kridx[2]];
      bf16x8 kf3 = *(const bf16x8*)&lds[base + kridx[3]];

      f32x16 st = __builtin_amdgcn_mfma_f32_32x32x16_bf16(kf0, qfrag[0], zro, 0, 0, 0);
      st = __builtin_amdgcn_mfma_f32_32x32x16_bf16(kf1, qfrag[1], st, 0, 0, 0);
      st = __builtin_amdgcn_mfma_f32_32x32x16_bf16(kf2, qfrag[2], st, 0, 0, 0);
      st = __builtin_amdgcn_mfma_f32_32x32x16_bf16(kf3, qfrag[3], st, 0, 0, 0);

      if (masked) {
#pragma unroll
        for (int rr = 0; rr < 16; ++rr) {
          const int kg = k0 + (rr & 3) + 8 * (rr >> 2) + 4 * hi;
          if (kg > q_glob) st[rr] = -1e30f;
        }
      }
      float m01 = fmaxf(fmaxf(st[0], st[1]), st[2]);
      float m02 = fmaxf(fmaxf(st[3], st[4]), st[5]);
      float m03 = fmaxf(fmaxf(st[6], st[7]), st[8]);
      float m04 = fmaxf(fmaxf(st[9], st[10]), st[11]);
      float m05 = fmaxf(fmaxf(st[12], st[13]), st[14]);
      float m06 = fmaxf(fmaxf(m01, m02), m03);
      float m07 = fmaxf(fmaxf(m04, m05), st[15]);
      const float bmax = fmaxf(m06, m07);
      if (__any(bmax > m_run + 8.f)) {        // T13 defer-max
        const float rmax = fmaxf(bmax, __shfl_xor(bmax, 32));
        const float mnew = fmaxf(m_run, rmax);
        const float corr = fexp2(m_run - mnew);
#pragma unroll
        for (int i = 0; i < 16; ++i) { acc0[i] *= corr; acc1[i] *= corr; }
        accL[0] *= corr;
        m_run = mnew;
      }
      float pp[16];
#pragma unroll
      for (int rr = 0; rr < 16; ++rr) pp[rr] = fexp2(st[rr] - m_run);

      // pack P^T B-fragments: HW cvt_pk + permlane32_swap
      unsigned w[8];
#pragma unroll
      for (int i = 0; i < 8; ++i) w[i] = cvtpk(pp[2 * i], pp[2 * i + 1]);
      plswap(w[0], w[2]); plswap(w[1], w[3]);
      plswap(w[4], w[6]); plswap(w[5], w[7]);
      union fu { unsigned u[4]; bf16x8 v; };
      fu f1, f2;
      f1.u[0] = w[0]; f1.u[1] = w[1]; f1.u[2] = w[2]; f1.u[3] = w[3];
      f2.u[0] = w[4]; f2.u[1] = w[5]; f2.u[2] = w[6]; f2.u[3] = w[7];

      bf16x8 vf0 = *(const bf16x8*)&lds[base + v0idx];
      bf16x8 vf1 = *(const bf16x8*)&lds[base + v1idx];
      bf16x8 vf2 = *(const bf16x8*)&lds[base + v2idx];
      bf16x8 vf3 = *(const bf16x8*)&lds[base + v3idx];

      acc0 = __builtin_amdgcn_mfma_f32_32x32x16_bf16(vf0, f1.v, acc0, 0, 0, 0);
      acc0 = __builtin_amdgcn_mfma_f32_32x32x16_bf16(vf1, f2.v, acc0, 0, 0, 0);
      acc1 = __builtin_amdgcn_mfma_f32_32x32x16_bf16(vf2, f1.v, acc1, 0, 0, 0);
      acc1 = __builtin_amdgcn_mfma_f32_32x32x16_bf16(vf3, f2.v, acc1, 0, 0, 0);
      // l-row: every acc reg of accL = sum_k P[q,k]; only [0] consumed
      accL = __builtin_amdgcn_mfma_f32_32x32x16_bf16(onesf.v, f1.v, accL, 0, 0, 0);
      accL = __builtin_amdgcn_mfma_f32_32x32x16_bf16(onesf.v, f2.v, accL, 0, 0, 0);
    }

    if (more) {
      const int nb = (buf ^ 1) * 512;
      lds[nb + wKidx] = kreg;
      lds[nb + wVidx] = vreg;
      pKn += (size_t)32 * LDQKV;
      pVn += 32;
    }
    __syncthreads();
    buf ^= 1;
  }

  // epilogue: O = acc / l  (l = accL[0], identical across half-lanes)
  const float inv = 1.f / accL[0];
  bf16_t* yrow = y + (size_t)(b * T_SEQ + q_glob) * D_MODEL + h * HD;
#pragma unroll
  for (int gg = 0; gg < 4; ++gg) {
    uint2 o0, o1;
    o0.x = cvtpk(acc0[4 * gg + 0] * inv, acc0[4 * gg + 1] * inv);
    o0.y = cvtpk(acc0[4 * gg + 2] * inv, acc0[4 * gg + 3] * inv);
    o1.x = cvtpk(acc1[4 * gg + 0] * inv, acc1[4 * gg + 1] * inv);
    o1.y = cvtpk(acc1[4 * gg + 2] * inv, acc1[4 * gg + 3] * inv);
    *(uint2*)(yrow + 8 * gg + 4 * hi)      = o0;
    *(uint2*)(yrow + 32 + 8 * gg + 4 * hi) = o1;
  }
}

// ---------------------------------------------------------------------------
extern "C" void kernel_launch(void* const* d_in, const int* in_sizes, int n_in,
                              void* d_out, int out_size, void* d_ws,
                              size_t ws_size, hipStream_t stream) {
  const float* x    = (const float*)d_in[0];
  const float* cosb = (const float*)d_in[1];
  const float* sinb = (const float*)d_in[2];
  const float* Wq   = (const float*)d_in[3];
  const float* Wk   = (const float*)d_in[4];
  const float* Wv   = (const float*)d_in[5];
  const float* Wo   = (const float*)d_in[6];
  const float* qs   = (const float*)d_in[7];
  const float* ks   = (const float*)d_in[8];
  float* out = (float*)d_out;   // reference output dtype is float32

  char* ws = (char*)d_ws;
  bf16_t* qkv   = (bf16_t*)ws;                       // 25165824 B
  bf16_t* v_t   = (bf16_t*)(ws + 25165824);          // 4194304 B
  bf16_t* y     = (bf16_t*)(ws + 29360128);          // 16777216 B (= xb alias)
  bf16_t* xb    = y;                                 // xb dead before attn writes y
  bf16_t* wqkvb = (bf16_t*)(ws + 46137344);          // 3145728 B
  bf16_t* wob   = (bf16_t*)(ws + 49283072);          // 2097152 B

  to_bf16<<<dim3(2048), 256, 0, stream>>>(x, xb, 524288);
  to_bf16<<<dim3(256),  256, 0, stream>>>(Wq, wqkvb, 65536);
  to_bf16<<<dim3(64),   256, 0, stream>>>(Wk, wqkvb + 1024 * 1024, 16384);
  to_bf16<<<dim3(64),   256, 0, stream>>>(Wv, wqkvb + 1280 * 1024, 16384);
  to_bf16<<<dim3(256),  256, 0, stream>>>(Wo, wob, 65536);

  gemm_bb<bf16_t><<<dim3(12, 64), 256, 0, stream>>>(xb, wqkvb, qkv, LDQKV);
  rms_rope<<<dim3(8192), 256, 0, stream>>>(qkv, cosb, sinb, qs, ks);
  v_transpose<<<dim3(16, 32), 256, 0, stream>>>(qkv, v_t);
  attn<<<dim3(1024), 256, 0, stream>>>(qkv, v_t, y);
  gemm_bb<float><<<dim3(8, 64), 256, 0, stream>>>(y, wob, out, D_MODEL);
}